// Round 6
// baseline (230.639 us; speedup 1.0000x reference)
//
#include <hip/hip_runtime.h>
#include <hip/hip_bf16.h>
#include <math.h>

#define N_NODES 50000
#define N_EDGES 800000
#define IN_F 256
#define HF 256      // NUM_HEADS * OUT_FEATS
#define NHEAD 4
#define OF 64
#define MPAD 50048  // 391 * 128
#define NPAD 50176  // 49 * 1024
#define NB 49       // scan blocks

typedef __attribute__((ext_vector_type(8))) short short8;
typedef __attribute__((ext_vector_type(4))) float f32x4;

// ---- explicit bf16 conversions ----
__device__ __forceinline__ ushort f32_to_bf16(float x) {
  unsigned u = __float_as_uint(x);
  u += 0x7FFFu + ((u >> 16) & 1u);   // round-to-nearest-even
  return (ushort)(u >> 16);
}

// async global->LDS, 16B per lane
__device__ __forceinline__ void gload_lds16(const void* g, void* l) {
  __builtin_amdgcn_global_load_lds(
      (const __attribute__((address_space(1))) unsigned int*)g,
      (__attribute__((address_space(3))) unsigned int*)l, 16, 0, 0);
}

// ---- prep: wlr[k][q] = sum_f W[k][h*64+f] * attn_{l,r}[h][f]  (q=h or 4+h) ----
// one wave per k-row; lanes hold 4 cols each (all in head lane>>4)
__global__ __launch_bounds__(256) void prep_wlr(const float* __restrict__ W,
                                                const float* __restrict__ al,
                                                const float* __restrict__ ar,
                                                float* __restrict__ wlr) {
  int w = threadIdx.x >> 6, lane = threadIdx.x & 63;
  int k = blockIdx.x * 4 + w;
  if (k >= HF) return;
  int h = lane >> 4;
  float4 wv = ((const float4*)(W + (size_t)k * HF))[lane];
  float4 av = ((const float4*)al)[lane];
  float4 rv = ((const float4*)ar)[lane];
  float pl = wv.x * av.x + wv.y * av.y + wv.z * av.z + wv.w * av.w;
  float pr = wv.x * rv.x + wv.y * rv.y + wv.z * rv.z + wv.w * rv.w;
#pragma unroll
  for (int off = 1; off < 16; off <<= 1) {
    pl += __shfl_xor(pl, off);
    pr += __shfl_xor(pr, off);
  }
  if ((lane & 15) == 0) {
    wlr[k * 8 + h] = pl;
    wlr[k * 8 + 4 + h] = pr;
  }
}

// ---- fused: feat->bf16 + direct el/er logits + W^T + degree histogram ----
// one wave per node
__global__ __launch_bounds__(256) void convert_row(const float* __restrict__ feat,
                                                   const float* __restrict__ W,
                                                   const int* __restrict__ dst,
                                                   const float* __restrict__ wlr,
                                                   ushort* __restrict__ feat_bf,
                                                   ushort* __restrict__ WT,
                                                   float* __restrict__ el,
                                                   float* __restrict__ er,
                                                   int* __restrict__ deg) {
  int w = threadIdx.x >> 6, lane = threadIdx.x & 63;
  int n = blockIdx.x * 4 + w;
  if (n < N_NODES) {
    float4 v = ((const float4*)(feat + (size_t)n * IN_F))[lane];
    ushort4 o;
    o.x = f32_to_bf16(v.x); o.y = f32_to_bf16(v.y);
    o.z = f32_to_bf16(v.z); o.w = f32_to_bf16(v.w);
    ((ushort4*)(feat_bf + (size_t)n * IN_F))[lane] = o;
    float acc[8] = {0.f, 0.f, 0.f, 0.f, 0.f, 0.f, 0.f, 0.f};
    const float* wp = wlr + lane * 4 * 8;
#pragma unroll
    for (int i = 0; i < 4; ++i) {
      float fv = ((const float*)&v)[i];
#pragma unroll
      for (int q = 0; q < 8; ++q) acc[q] += fv * wp[i * 8 + q];
    }
#pragma unroll
    for (int q = 0; q < 8; ++q) {
#pragma unroll
      for (int off = 32; off > 0; off >>= 1) acc[q] += __shfl_xor(acc[q], off);
    }
    if (lane == 0) {
      *(float4*)&el[n * NHEAD] = float4{acc[0], acc[1], acc[2], acc[3]};
      *(float4*)&er[n * NHEAD] = float4{acc[4], acc[5], acc[6], acc[7]};
    }
  }
  int gtid = blockIdx.x * blockDim.x + threadIdx.x;
  int stride = gridDim.x * blockDim.x;
  for (int j = gtid; j < IN_F * HF; j += stride) {
    int nn = j >> 8, k = j & 255;                 // WT[nn][k] = W[k][nn]
    WT[j] = f32_to_bf16(W[k * HF + nn]);
  }
  for (int e = gtid; e < N_EDGES; e += stride)
    atomicAdd(&deg[dst[e]], 1);
}

// ---- bf16 MFMA GEMM: ft[MPAD,256] = feat_bf[M,256] @ WT^T ----
__global__ __launch_bounds__(256) void gemm_mfma(const ushort* __restrict__ A,
                                                 const ushort* __restrict__ BT,
                                                 ushort* __restrict__ C) {
  __shared__ char lds[16384];               // As 8KB | Bs 8KB
  char* As = lds;
  char* Bs = lds + 8192;
  int tid = threadIdx.x;
  int w = tid >> 6, lane = tid & 63;
  int brow = blockIdx.x * 128;
  int bcol = blockIdx.y * 128;
  int wr = w >> 1, wc = w & 1;
  f32x4 acc[4][4];
#pragma unroll
  for (int m = 0; m < 4; ++m)
#pragma unroll
    for (int n = 0; n < 4; ++n) acc[m][n] = (f32x4){0.f, 0.f, 0.f, 0.f};

  int rl = lane & 15, khalf = lane >> 4;
  for (int k0 = 0; k0 < IN_F; k0 += 32) {
#pragma unroll
    for (int part = 0; part < 2; ++part) {
      int ii = w * 2 + part;
      int off = ii * 1024 + lane * 16;
      int trow = off >> 6, inb = (off & 63) >> 1;
      int ga = min(brow + trow, N_NODES - 1);
      gload_lds16(A + (size_t)ga * IN_F + k0 + inb, As + ii * 1024);
      gload_lds16(BT + (size_t)(bcol + trow) * IN_F + k0 + inb, Bs + ii * 1024);
    }
    __syncthreads();
    short8 a[4], b[4];
#pragma unroll
    for (int m = 0; m < 4; ++m)
      a[m] = *(const short8*)(As + (((wr * 64 + m * 16 + rl) << 6) | (khalf << 4)));
#pragma unroll
    for (int n = 0; n < 4; ++n)
      b[n] = *(const short8*)(Bs + (((wc * 64 + n * 16 + rl) << 6) | (khalf << 4)));
#pragma unroll
    for (int m = 0; m < 4; ++m)
#pragma unroll
      for (int n = 0; n < 4; ++n)
        acc[m][n] = __builtin_amdgcn_mfma_f32_16x16x32_bf16(a[m], b[n], acc[m][n], 0, 0, 0);
    __syncthreads();
  }
#pragma unroll
  for (int m = 0; m < 4; ++m) {
    int r0 = brow + wr * 64 + m * 16 + khalf * 4;
#pragma unroll
    for (int n = 0; n < 4; ++n) {
      int col = bcol + wc * 64 + n * 16 + rl;
#pragma unroll
      for (int j = 0; j < 4; ++j)
        C[(size_t)(r0 + j) * HF + col] = f32_to_bf16(acc[m][n][j]);
    }
  }
}

// ---- hierarchical scan: deg -> row_start (exclusive) ----
__global__ __launch_bounds__(256) void scan1(const int* __restrict__ deg,
                                             int* __restrict__ rowst,
                                             int* __restrict__ bsum) {
  __shared__ int wsum[4];
  int t = threadIdx.x, b = blockIdx.x;
  int lane = t & 63, wid = t >> 6;
  int i0 = b * 1024 + t * 4;
  int4 v = ((const int4*)deg)[i0 >> 2];
  int s = v.x + v.y + v.z + v.w;
  int incl = s;
#pragma unroll
  for (int off = 1; off < 64; off <<= 1) {
    int tmp = __shfl_up(incl, off);
    if (lane >= off) incl += tmp;
  }
  if (lane == 63) wsum[wid] = incl;
  __syncthreads();
  int woff = 0;
#pragma unroll
  for (int ww = 0; ww < 4; ++ww) if (ww < wid) woff += wsum[ww];
  int e0 = woff + incl - s;
  int4 o = {e0, e0 + v.x, e0 + v.x + v.y, e0 + v.x + v.y + v.z};
  ((int4*)rowst)[i0 >> 2] = o;
  if (t == 255) bsum[b] = woff + incl;
}

__global__ __launch_bounds__(64) void scan2(const int* __restrict__ bsum,
                                            int* __restrict__ boff) {
  int lane = threadIdx.x;
  int v = (lane < NB) ? bsum[lane] : 0;
  int incl = v;
#pragma unroll
  for (int off = 1; off < 64; off <<= 1) {
    int tmp = __shfl_up(incl, off);
    if (lane >= off) incl += tmp;
  }
  if (lane < NB) boff[lane] = incl - v;
}

__global__ __launch_bounds__(256) void scan3(int* __restrict__ rowst,
                                             int* __restrict__ cursor,
                                             const int* __restrict__ boff) {
  int t = threadIdx.x, b = blockIdx.x;
  int i0 = b * 1024 + t * 4;
  int4 r = ((const int4*)rowst)[i0 >> 2];
  int o = boff[b];
  r.x += o; r.y += o; r.z += o; r.w += o;
  ((int4*)rowst)[i0 >> 2] = r;
  ((int4*)cursor)[i0 >> 2] = r;
}

// ---- fill: CSR src permutation only ----
__global__ __launch_bounds__(256) void fill_src(const int* __restrict__ src,
                                                const int* __restrict__ dst,
                                                int* __restrict__ cursor,
                                                int* __restrict__ csr_src) {
  int stride = gridDim.x * blockDim.x;
  for (int e = blockIdx.x * blockDim.x + threadIdx.x; e < N_EDGES; e += stride) {
    int p = atomicAdd(&cursor[dst[e]], 1);
    csr_src[p] = src[e];
  }
}

// ---- aggregate: one wave per dst; exp computed in-register; single store ----
__global__ __launch_bounds__(256) void aggregate(const int* __restrict__ rowst,
                                                 const int* __restrict__ csr_src,
                                                 const float* __restrict__ el,
                                                 const float* __restrict__ er,
                                                 const ushort* __restrict__ ft,
                                                 float* __restrict__ out) {
  int w = threadIdx.x >> 6, lane = threadIdx.x & 63;
  int n = blockIdx.x * 4 + w;
  if (n >= N_NODES) return;
  int h = lane >> 4;      // head for this lane
  int c = lane << 2;      // column 0..252
  float erh = er[n * NHEAD + h];
  int j0 = rowst[n], j1 = rowst[n + 1];
  float a0x = 0.f, a0y = 0.f, a0z = 0.f, a0w = 0.f, den0 = 0.f;
  float a1x = 0.f, a1y = 0.f, a1z = 0.f, a1w = 0.f, den1 = 0.f;
  int j = j0;
  for (; j + 1 < j1; j += 2) {
    int s0 = csr_src[j], s1 = csr_src[j + 1];
    float x0 = el[s0 * NHEAD + h] + erh;
    float x1 = el[s1 * NHEAD + h] + erh;
    x0 = x0 > 0.f ? x0 : 0.2f * x0;
    x1 = x1 > 0.f ? x1 : 0.2f * x1;
    float a0 = __expf(x0), a1 = __expf(x1);
    uint2 u0 = *(const uint2*)(ft + (size_t)s0 * HF + c);
    uint2 u1 = *(const uint2*)(ft + (size_t)s1 * HF + c);
    den0 += a0; den1 += a1;
    a0x += __uint_as_float(u0.x << 16) * a0;
    a0y += __uint_as_float(u0.x & 0xFFFF0000u) * a0;
    a0z += __uint_as_float(u0.y << 16) * a0;
    a0w += __uint_as_float(u0.y & 0xFFFF0000u) * a0;
    a1x += __uint_as_float(u1.x << 16) * a1;
    a1y += __uint_as_float(u1.x & 0xFFFF0000u) * a1;
    a1z += __uint_as_float(u1.y << 16) * a1;
    a1w += __uint_as_float(u1.y & 0xFFFF0000u) * a1;
  }
  if (j < j1) {
    int s0 = csr_src[j];
    float x0 = el[s0 * NHEAD + h] + erh;
    x0 = x0 > 0.f ? x0 : 0.2f * x0;
    float a0 = __expf(x0);
    uint2 u0 = *(const uint2*)(ft + (size_t)s0 * HF + c);
    den0 += a0;
    a0x += __uint_as_float(u0.x << 16) * a0;
    a0y += __uint_as_float(u0.x & 0xFFFF0000u) * a0;
    a0z += __uint_as_float(u0.y << 16) * a0;
    a0w += __uint_as_float(u0.y & 0xFFFF0000u) * a0;
  }
  float den = den0 + den1;
  float inv = den > 0.f ? 1.0f / den : 0.f;   // degree-0 nodes -> 0 (matches ref)
  float4 r = {(a0x + a1x) * inv, (a0y + a1y) * inv, (a0z + a1z) * inv, (a0w + a1w) * inv};
  *(float4*)&out[(size_t)n * HF + c] = r;
}

extern "C" void kernel_launch(void* const* d_in, const int* in_sizes, int n_in,
                              void* d_out, int out_size, void* d_ws, size_t ws_size,
                              hipStream_t stream) {
  const float* feat = (const float*)d_in[0];
  const int*   src  = (const int*)d_in[1];
  const int*   dst  = (const int*)d_in[2];
  const float* W    = (const float*)d_in[3];
  const float* al   = (const float*)d_in[4];
  const float* ar   = (const float*)d_in[5];
  float* out = (float*)d_out;

  char* ws = (char*)d_ws;
  ushort* ft_bf   = (ushort*)(ws);                    // 25,624,576 B (MPAD rows)
  ushort* feat_bf = (ushort*)(ws + 26000000);         // 25,600,000 B
  int*    csr_src = (int*)(ws + 26000000);            // aliased (feat_bf dead after gemm)
  ushort* WT      = (ushort*)(ws + 51600000);         //    131,072 B
  float*  wlr     = (float*)(ws + 51800000);          //      8,192 B
  float*  el      = (float*)(ws + 52000000);          //    800,000 B
  float*  er      = (float*)(ws + 52800000);          //    800,000 B
  int*    deg     = (int*)(ws + 53600000);            //    200,704 B (NPAD)
  int*    cursor  = (int*)(ws + 53800704);            //    200,704 B
  int*    rowst   = (int*)(ws + 54001408);            //    200,704 B
  int*    bsum    = (int*)(ws + 54202112);            //        196 B
  int*    boff    = (int*)(ws + 54202368);            //        196 B

  hipMemsetAsync(deg, 0, NPAD * sizeof(int), stream);
  prep_wlr<<<64, 256, 0, stream>>>(W, al, ar, wlr);
  convert_row<<<12500, 256, 0, stream>>>(feat, W, dst, wlr, feat_bf, WT, el, er, deg);
  dim3 ggrid(MPAD / 128, HF / 128);
  gemm_mfma<<<ggrid, 256, 0, stream>>>(feat_bf, WT, ft_bf);
  scan1<<<NB, 256, 0, stream>>>(deg, rowst, bsum);
  scan2<<<1, 64, 0, stream>>>(bsum, boff);
  scan3<<<NB, 256, 0, stream>>>(rowst, cursor, boff);
  fill_src<<<3125, 256, 0, stream>>>(src, dst, cursor, csr_src);
  aggregate<<<(N_NODES + 3) / 4, 256, 0, stream>>>(rowst, csr_src, el, er, ft_bf, out);
}

// Round 7
// 223.720 us; speedup vs baseline: 1.0309x; 1.0309x over previous
//
#include <hip/hip_runtime.h>
#include <hip/hip_bf16.h>
#include <math.h>

#define N_NODES 50000
#define N_EDGES 800000
#define IN_F 256
#define HF 256      // NUM_HEADS * OUT_FEATS
#define NHEAD 4
#define OF 64
#define MPAD 50048  // 391 * 128
#define NPAD 50176  // 49 * 1024
#define NB 49       // scan blocks

typedef __attribute__((ext_vector_type(8))) short short8;
typedef __attribute__((ext_vector_type(4))) float f32x4;

// ---- explicit bf16 conversions ----
__device__ __forceinline__ ushort f32_to_bf16(float x) {
  unsigned u = __float_as_uint(x);
  u += 0x7FFFu + ((u >> 16) & 1u);   // round-to-nearest-even
  return (ushort)(u >> 16);
}
__device__ __forceinline__ float bfl(unsigned u) { return __uint_as_float(u << 16); }
__device__ __forceinline__ float bfh(unsigned u) { return __uint_as_float(u & 0xFFFF0000u); }

// async global->LDS, 16B per lane
__device__ __forceinline__ void gload_lds16(const void* g, void* l) {
  __builtin_amdgcn_global_load_lds(
      (const __attribute__((address_space(1))) unsigned int*)g,
      (__attribute__((address_space(3))) unsigned int*)l, 16, 0, 0);
}

// ---- fused: feat->bf16, W->W^T bf16, dst degree histogram ----
__global__ __launch_bounds__(256) void convert_count(const float* __restrict__ feat,
                                                     const float* __restrict__ W,
                                                     const int* __restrict__ dst,
                                                     ushort* __restrict__ feat_bf,
                                                     ushort* __restrict__ WT,
                                                     int* __restrict__ deg) {
  int stride = gridDim.x * blockDim.x;
  int i = blockIdx.x * blockDim.x + threadIdx.x;
  int n4 = N_NODES * IN_F / 4;
  for (int j = i; j < n4; j += stride) {
    float4 v = ((const float4*)feat)[j];
    ushort4 o;
    o.x = f32_to_bf16(v.x); o.y = f32_to_bf16(v.y);
    o.z = f32_to_bf16(v.z); o.w = f32_to_bf16(v.w);
    ((ushort4*)feat_bf)[j] = o;
  }
  for (int j = i; j < IN_F * HF; j += stride) {
    int n = j >> 8, k = j & 255;                 // WT[n][k] = W[k][n]
    WT[j] = f32_to_bf16(W[k * HF + n]);
  }
  for (int e = i; e < N_EDGES; e += stride)
    atomicAdd(&deg[dst[e]], 1);
}

// ---- bf16 MFMA GEMM: ft[MPAD,256] = feat_bf[M,256] @ WT^T ----
__global__ __launch_bounds__(256) void gemm_mfma(const ushort* __restrict__ A,
                                                 const ushort* __restrict__ BT,
                                                 ushort* __restrict__ C) {
  __shared__ char lds[16384];               // As 8KB | Bs 8KB
  char* As = lds;
  char* Bs = lds + 8192;
  int tid = threadIdx.x;
  int w = tid >> 6, lane = tid & 63;
  int brow = blockIdx.x * 128;
  int bcol = blockIdx.y * 128;
  int wr = w >> 1, wc = w & 1;
  f32x4 acc[4][4];
#pragma unroll
  for (int m = 0; m < 4; ++m)
#pragma unroll
    for (int n = 0; n < 4; ++n) acc[m][n] = (f32x4){0.f, 0.f, 0.f, 0.f};

  int rl = lane & 15, khalf = lane >> 4;
  for (int k0 = 0; k0 < IN_F; k0 += 32) {
#pragma unroll
    for (int part = 0; part < 2; ++part) {
      int ii = w * 2 + part;
      int off = ii * 1024 + lane * 16;
      int trow = off >> 6, inb = (off & 63) >> 1;
      int ga = min(brow + trow, N_NODES - 1);
      gload_lds16(A + (size_t)ga * IN_F + k0 + inb, As + ii * 1024);
      gload_lds16(BT + (size_t)(bcol + trow) * IN_F + k0 + inb, Bs + ii * 1024);
    }
    __syncthreads();
    short8 a[4], b[4];
#pragma unroll
    for (int m = 0; m < 4; ++m)
      a[m] = *(const short8*)(As + (((wr * 64 + m * 16 + rl) << 6) | (khalf << 4)));
#pragma unroll
    for (int n = 0; n < 4; ++n)
      b[n] = *(const short8*)(Bs + (((wc * 64 + n * 16 + rl) << 6) | (khalf << 4)));
#pragma unroll
    for (int m = 0; m < 4; ++m)
#pragma unroll
      for (int n = 0; n < 4; ++n)
        acc[m][n] = __builtin_amdgcn_mfma_f32_16x16x32_bf16(a[m], b[n], acc[m][n], 0, 0, 0);
    __syncthreads();
  }
#pragma unroll
  for (int m = 0; m < 4; ++m) {
    int r0 = brow + wr * 64 + m * 16 + khalf * 4;
#pragma unroll
    for (int n = 0; n < 4; ++n) {
      int col = bcol + wc * 64 + n * 16 + rl;
#pragma unroll
      for (int j = 0; j < 4; ++j)
        C[(size_t)(r0 + j) * HF + col] = f32_to_bf16(acc[m][n][j]);
    }
  }
}

// ---- per-node logits from bf16 ft ----
__global__ __launch_bounds__(256) void node_logits(const ushort* __restrict__ ft,
                                                   const float* __restrict__ al,
                                                   const float* __restrict__ ar,
                                                   float* __restrict__ el,
                                                   float* __restrict__ er) {
  int t = threadIdx.x;
  int h = t >> 6, f = t & 63;
  float wl = al[h * OF + f], wr = ar[h * OF + f];
  for (int n = blockIdx.x; n < N_NODES; n += gridDim.x) {
    float v = bfl((unsigned)ft[(size_t)n * HF + t]) ;
    float pl = v * wl, pr = v * wr;
#pragma unroll
    for (int off = 32; off > 0; off >>= 1) {
      pl += __shfl_xor(pl, off);
      pr += __shfl_xor(pr, off);
    }
    if (f == 0) { el[n * NHEAD + h] = pl; er[n * NHEAD + h] = pr; }
  }
}

// ---- scan step 1: per-block exclusive scan of deg + block totals ----
__global__ __launch_bounds__(256) void scan1(const int* __restrict__ deg,
                                             int* __restrict__ rowst,
                                             int* __restrict__ bsum) {
  __shared__ int wsum[4];
  int t = threadIdx.x, b = blockIdx.x;
  int lane = t & 63, wid = t >> 6;
  int i0 = b * 1024 + t * 4;
  int4 v = ((const int4*)deg)[i0 >> 2];
  int s = v.x + v.y + v.z + v.w;
  int incl = s;
#pragma unroll
  for (int off = 1; off < 64; off <<= 1) {
    int tmp = __shfl_up(incl, off);
    if (lane >= off) incl += tmp;
  }
  if (lane == 63) wsum[wid] = incl;
  __syncthreads();
  int woff = 0;
#pragma unroll
  for (int ww = 0; ww < 4; ++ww) if (ww < wid) woff += wsum[ww];
  int e0 = woff + incl - s;
  int4 o = {e0, e0 + v.x, e0 + v.x + v.y, e0 + v.x + v.y + v.z};
  ((int4*)rowst)[i0 >> 2] = o;
  if (t == 255) bsum[b] = woff + incl;
}

// ---- scan step 2 (merged): add predecessor-block totals; write cursor ----
__global__ __launch_bounds__(256) void scan3(int* __restrict__ rowst,
                                             int* __restrict__ cursor,
                                             const int* __restrict__ bsum) {
  int t = threadIdx.x, b = blockIdx.x;
  int o = 0;
  for (int k = 0; k < b; ++k) o += bsum[k];   // NB<=49, uniform scalar loop
  int i0 = b * 1024 + t * 4;
  int4 r = ((const int4*)rowst)[i0 >> 2];
  r.x += o; r.y += o; r.z += o; r.w += o;
  ((int4*)rowst)[i0 >> 2] = r;
  ((int4*)cursor)[i0 >> 2] = r;
}

// ---- fill: CSR src permutation only ----
__global__ __launch_bounds__(256) void fill_src(const int* __restrict__ src,
                                                const int* __restrict__ dst,
                                                int* __restrict__ cursor,
                                                int* __restrict__ csr_src) {
  int stride = gridDim.x * blockDim.x;
  for (int e = blockIdx.x * blockDim.x + threadIdx.x; e < N_EDGES; e += stride) {
    int p = atomicAdd(&cursor[dst[e]], 1);
    csr_src[p] = src[e];
  }
}

// ---- aggregate v2: wave per node, half-wave per edge, 16B ft loads ----
__global__ __launch_bounds__(256) void aggregate(const int* __restrict__ rowst,
                                                 const int* __restrict__ csr_src,
                                                 const float* __restrict__ el,
                                                 const float* __restrict__ er,
                                                 const ushort* __restrict__ ft,
                                                 float* __restrict__ out) {
  int w = threadIdx.x >> 6, lane = threadIdx.x & 63;
  int n = blockIdx.x * 4 + w;
  if (n >= N_NODES) return;
  int half = lane >> 5, l5 = lane & 31;
  int h = l5 >> 3;        // head for this lane's 8 columns
  int c = l5 << 3;        // column base 0..248
  float erh = er[n * NHEAD + h];
  int j0 = rowst[n], j1 = rowst[n + 1];
  float a0 = 0.f, a1 = 0.f, a2 = 0.f, a3 = 0.f;
  float a4 = 0.f, a5 = 0.f, a6 = 0.f, a7 = 0.f;
  float den = 0.f;
#pragma unroll 2
  for (int j = j0 + half; j < j1; j += 2) {
    int s = csr_src[j];
    float x = el[s * NHEAD + h] + erh;
    x = x > 0.f ? x : 0.2f * x;
    float a = __expf(x);
    den += a;
    uint4 u = *(const uint4*)(ft + (size_t)s * HF + c);
    a0 += bfl(u.x) * a; a1 += bfh(u.x) * a;
    a2 += bfl(u.y) * a; a3 += bfh(u.y) * a;
    a4 += bfl(u.z) * a; a5 += bfh(u.z) * a;
    a6 += bfl(u.w) * a; a7 += bfh(u.w) * a;
  }
  // merge the two half-wave partials (lane i <-> lane i+32 hold same columns)
  den += __shfl_xor(den, 32);
  a0 += __shfl_xor(a0, 32); a1 += __shfl_xor(a1, 32);
  a2 += __shfl_xor(a2, 32); a3 += __shfl_xor(a3, 32);
  a4 += __shfl_xor(a4, 32); a5 += __shfl_xor(a5, 32);
  a6 += __shfl_xor(a6, 32); a7 += __shfl_xor(a7, 32);
  if (half == 0) {
    float inv = den > 0.f ? 1.0f / den : 0.f;   // degree-0 -> 0 (matches ref)
    float4 r0 = {a0 * inv, a1 * inv, a2 * inv, a3 * inv};
    float4 r1 = {a4 * inv, a5 * inv, a6 * inv, a7 * inv};
    *(float4*)&out[(size_t)n * HF + c] = r0;
    *(float4*)&out[(size_t)n * HF + c + 4] = r1;
  }
}

extern "C" void kernel_launch(void* const* d_in, const int* in_sizes, int n_in,
                              void* d_out, int out_size, void* d_ws, size_t ws_size,
                              hipStream_t stream) {
  const float* feat = (const float*)d_in[0];
  const int*   src  = (const int*)d_in[1];
  const int*   dst  = (const int*)d_in[2];
  const float* W    = (const float*)d_in[3];
  const float* al   = (const float*)d_in[4];
  const float* ar   = (const float*)d_in[5];
  float* out = (float*)d_out;

  char* ws = (char*)d_ws;
  ushort* ft_bf   = (ushort*)(ws);                    // 25,624,576 B (MPAD rows)
  ushort* feat_bf = (ushort*)(ws + 26000000);         // 25,600,000 B
  int*    csr_src = (int*)(ws + 26000000);            // aliased (feat_bf dead after gemm)
  ushort* WT      = (ushort*)(ws + 51600000);         //    131,072 B
  float*  el      = (float*)(ws + 52000000);          //    800,000 B
  float*  er      = (float*)(ws + 52800000);          //    800,000 B
  int*    deg     = (int*)(ws + 53600000);            //    200,704 B (NPAD)
  int*    cursor  = (int*)(ws + 53800704);            //    200,704 B
  int*    rowst   = (int*)(ws + 54001408);            //    200,704 B
  int*    bsum    = (int*)(ws + 54202112);            //        196 B

  hipMemsetAsync(deg, 0, NPAD * sizeof(int), stream);
  convert_count<<<2048, 256, 0, stream>>>(feat, W, dst, feat_bf, WT, deg);
  dim3 ggrid(MPAD / 128, HF / 128);
  gemm_mfma<<<ggrid, 256, 0, stream>>>(feat_bf, WT, ft_bf);
  node_logits<<<2048, 256, 0, stream>>>(ft_bf, al, ar, el, er);
  scan1<<<NB, 256, 0, stream>>>(deg, rowst, bsum);
  scan3<<<NB, 256, 0, stream>>>(rowst, cursor, bsum);
  fill_src<<<3125, 256, 0, stream>>>(src, dst, cursor, csr_src);
  aggregate<<<(N_NODES + 3) / 4, 256, 0, stream>>>(rowst, csr_src, el, er, ft_bf, out);
}